// Round 1
// baseline (109.385 us; speedup 1.0000x reference)
//
#include <hip/hip_runtime.h>

#define KN 64
#define DIN 128
#define DOUT 128
#define NJ 63            // K-1 intervals
#define EPSF 1e-12f

// Packed table in d_ws: float4 pk[DIN][NJ][DOUT] = (y0, d0, y1, d1)
// 128*63*128*16 B = 16,515,072 B (~16.5 MB)

__global__ __launch_bounds__(256) void kan_precompute(
    const float* __restrict__ coeffs,   // [DOUT][DIN][KN]
    const float* __restrict__ knots,    // [KN]
    float4* __restrict__ pk)
{
    const int wave = threadIdx.x >> 6;          // 0..3
    const int lane = threadIdx.x & 63;          // = knot index k
    const int i = blockIdx.x & 127;             // input dim
    const int o = ((blockIdx.x >> 7) << 2) + wave;  // output dim

    float y  = coeffs[(o * DIN + i) * KN + lane];
    float kn  = knots[lane];
    float kn1 = (lane < 63) ? knots[lane + 1] : 0.0f;
    float hk  = kn1 - kn;                       // h[k], valid lanes 0..62

    float ynext = __shfl_down(y, 1);
    float delta = (lane < 63) ? (ynext - y) / (hk + EPSF) : 0.0f;

    float dm1 = __shfl_up(delta, 1);            // delta[k-1]
    float hm1 = __shfl_up(hk, 1);               // h[k-1]

    // interior slopes (valid for lanes 1..62)
    float w1v = 2.0f * hk + hm1;
    float w2v = hk + 2.0f * hm1;
    float denom = w1v / (dm1 + EPSF) + w2v / (delta + EPSF);
    float d = (dm1 * delta > 0.0f) ? (w1v + w2v) / (denom + EPSF) : 0.0f;

    // endpoint: first (lane 0)
    float d1v = __shfl_down(delta, 1);          // delta[1]
    float h1v = __shfl_down(hk, 1);             // h[1]
    if (lane == 0) {
        float df = ((2.0f * hk + h1v) * delta - hk * d1v) / (hk + h1v + EPSF);
        if (df * delta <= 0.0f) df = 0.0f;
        else if (fabsf(df) > 3.0f * fabsf(delta)) df = 3.0f * delta;
        d = df;
    }
    // endpoint: last (lane 63): delta[62]=dm1, h[62]=hm1, delta[61], h[61]
    float dm2 = __shfl_up(delta, 2);
    float hm2 = __shfl_up(hk, 2);
    if (lane == 63) {
        float dl = ((2.0f * hm1 + hm2) * dm1 - hm1 * dm2) / (hm1 + hm2 + EPSF);
        if (dl * dm1 <= 0.0f) dl = 0.0f;
        else if (fabsf(dl) > 3.0f * fabsf(dm1)) dl = 3.0f * dm1;
        d = dl;
    }

    // pack (y_j, d_j, y_{j+1}, d_{j+1}) for interval j = lane (0..62)
    float ynx = __shfl_down(y, 1);
    float dnx = __shfl_down(d, 1);
    if (lane < NJ) {
        pk[(i * NJ + lane) * DOUT + o] = make_float4(y, d, ynx, dnx);
    }
}

__global__ __launch_bounds__(128) void kan_main(
    const float* __restrict__ x,        // [B][DIN]
    const float4* __restrict__ pk,      // [DIN][NJ][DOUT]
    const float* __restrict__ bias,     // [DOUT]
    float* __restrict__ out)            // [B][DOUT]
{
    const int b = blockIdx.x;
    const int o = threadIdx.x;          // 0..127

    __shared__ float4 wts[DIN];
    __shared__ int    idxs[DIN];

    const float h = 1.0f / 63.0f;       // (X_MAX-X_MIN)/(K-1), f32 like ref

    // Phase 1: thread t computes weights for input dim i = t
    float xv = x[b * DIN + o];
    float xc = fminf(fmaxf(xv, 0.0f), 1.0f);
    int idx = (int)floorf(xc / h);
    idx = idx < 0 ? 0 : (idx > 62 ? 62 : idx);
    float t = (xc - (float)idx * h) / h;
    float t2 = t * t, t3 = t2 * t;
    float w0 = 2.0f * t3 - 3.0f * t2 + 1.0f;
    float w1 = (t3 - 2.0f * t2 + t) * h;
    float w2 = 3.0f * t2 - 2.0f * t3;
    float w3 = (t3 - t2) * h;
    if (xv < 0.0f)      { w0 = 1.0f; w1 = xv;        w2 = 0.0f; w3 = 0.0f;      idx = 0;  }
    else if (xv > 1.0f) { w0 = 0.0f; w1 = 0.0f;      w2 = 1.0f; w3 = xv - 1.0f; idx = 62; }
    wts[o]  = make_float4(w0, w1, w2, w3);
    idxs[o] = idx;
    __syncthreads();

    // Phase 2: gather + accumulate
    float acc0 = 0.0f, acc1 = 0.0f, acc2 = 0.0f, acc3 = 0.0f;
    #pragma unroll 4
    for (int i = 0; i < DIN; i += 4) {
        float4 wA = wts[i];     int jA = idxs[i];
        float4 wB = wts[i + 1]; int jB = idxs[i + 1];
        float4 wC = wts[i + 2]; int jC = idxs[i + 2];
        float4 wD = wts[i + 3]; int jD = idxs[i + 3];
        float4 fA = pk[((i    ) * NJ + jA) * DOUT + o];
        float4 fB = pk[((i + 1) * NJ + jB) * DOUT + o];
        float4 fC = pk[((i + 2) * NJ + jC) * DOUT + o];
        float4 fD = pk[((i + 3) * NJ + jD) * DOUT + o];
        acc0 += wA.x * fA.x + wA.y * fA.y + wA.z * fA.z + wA.w * fA.w;
        acc1 += wB.x * fB.x + wB.y * fB.y + wB.z * fB.z + wB.w * fB.w;
        acc2 += wC.x * fC.x + wC.y * fC.y + wC.z * fC.z + wC.w * fC.w;
        acc3 += wD.x * fD.x + wD.y * fD.y + wD.z * fD.z + wD.w * fD.w;
    }

    out[b * DOUT + o] = acc0 + acc1 + acc2 + acc3 + bias[o];
}

extern "C" void kernel_launch(void* const* d_in, const int* in_sizes, int n_in,
                              void* d_out, int out_size, void* d_ws, size_t ws_size,
                              hipStream_t stream) {
    const float* x      = (const float*)d_in[0];   // 4096*128
    const float* coeffs = (const float*)d_in[1];   // 128*128*64
    const float* bias   = (const float*)d_in[2];   // 128
    const float* knots  = (const float*)d_in[3];   // 64
    float* out = (float*)d_out;
    float4* pk = (float4*)d_ws;                    // needs ~16.5 MB

    // precompute: 16384 (o,i) rows, one wave each -> 4096 blocks * 4 waves
    kan_precompute<<<4096, 256, 0, stream>>>(coeffs, knots, pk);
    // main: one block per batch row
    kan_main<<<4096, 128, 0, stream>>>(x, pk, bias, out);
}